// Round 7
// baseline (166.159 us; speedup 1.0000x reference)
//
#include <hip/hip_runtime.h>
#include <hip/hip_bf16.h>

typedef float f32x4 __attribute__((ext_vector_type(4)));
typedef __bf16 bf16x8 __attribute__((ext_vector_type(8)));
typedef unsigned short u16x8 __attribute__((ext_vector_type(8)));
typedef int i32x4 __attribute__((ext_vector_type(4)));

#define NEG_BIG_F (-1000000000.0f)
#define SCALE_F 0.044194173824159216f

__device__ __forceinline__ unsigned short f2bf(float f) {
  unsigned int u = __float_as_uint(f);
  u += 0x7FFFu + ((u >> 16) & 1u);   // round-to-nearest-even
  return (unsigned short)(u >> 16);
}

__device__ __forceinline__ float bf2f(unsigned short h) {
  return __uint_as_float((unsigned int)h << 16);
}

__device__ __forceinline__ u16x8 cvt8(f32x4 a, f32x4 b) {
  u16x8 r;
  r[0] = f2bf(a[0]); r[1] = f2bf(a[1]); r[2] = f2bf(a[2]); r[3] = f2bf(a[3]);
  r[4] = f2bf(b[0]); r[5] = f2bf(b[1]); r[6] = f2bf(b[2]); r[7] = f2bf(b[3]);
  return r;
}

__device__ __forceinline__ void gload16(const void* g, char* l) {
  __builtin_amdgcn_global_load_lds(
      (const __attribute__((address_space(1))) unsigned int*)g,
      (__attribute__((address_space(3))) unsigned int*)l, 16, 0, 0);
}

// ---------------------------------------------------------------------------
// cvtW: three 512x512 fp32 weight matrices -> bf16
// ---------------------------------------------------------------------------
__global__ __launch_bounds__(256) void cvtW(
    const float* __restrict__ w0, const float* __restrict__ w1,
    const float* __restrict__ w2, unsigned short* __restrict__ out)
{
  const float* src = blockIdx.z == 0 ? w0 : (blockIdx.z == 1 ? w1 : w2);
  unsigned short* dst = out + (size_t)blockIdx.z * 262144;
  const int i = (blockIdx.x * 256 + threadIdx.x) * 8;
  f32x4 a = *(const f32x4*)(src + i);
  f32x4 b = *(const f32x4*)(src + i + 4);
  *(u16x8*)&dst[i] = cvt8(a, b);
}

// ---------------------------------------------------------------------------
// projqk: z=0: qb = Q·WQ^T, z=1: kb = K·WK^T. 256x256 tile, BK=32, 512 thr.
// Counted-vmcnt two-barrier loop (unchanged from R6).
// ---------------------------------------------------------------------------
__global__ __launch_bounds__(512, 2) void projqk(
    const float* __restrict__ Q, const float* __restrict__ Kx,
    const unsigned short* __restrict__ wb,
    unsigned short* __restrict__ qb, unsigned short* __restrict__ kb)
{
  __shared__ __align__(16) unsigned short As[2][256][32];
  __shared__ __align__(16) unsigned short Bs[2][256][32];

  const int tid = threadIdx.x, z = blockIdx.z;
  const float* X = z ? Kx : Q;
  const unsigned short* W = wb + (size_t)z * 262144;
  unsigned short* Y = z ? kb : qb;
  const int m0 = blockIdx.x * 256, n0 = blockIdx.y * 256;
  const int lane = tid & 63, wave = tid >> 6;
  const int wr = (wave >> 2) * 128, wc = (wave & 3) * 64;
  const int fr = lane & 15, fq = lane >> 4;

  f32x4 acc[8][4] = {};

  int arow_s[2], aswz_s[2];
  const float* gAs[2];
  #pragma unroll
  for (int i = 0; i < 2; i++) {
    const int c = tid + 512 * i;
    arow_s[i] = c >> 2;
    aswz_s[i] = ((c & 3) ^ ((arow_s[i] >> 1) & 3)) * 8;
    gAs[i] = X + (size_t)(m0 + arow_s[i]) * 512 + (c & 3) * 8;
  }
  const unsigned short* gB[2]; char* lB[2];
  #pragma unroll
  for (int i = 0; i < 2; i++) {
    const int c = tid + 512 * i, row = c >> 2, slot = c & 3;
    gB[i] = W + (size_t)(n0 + row) * 512 + (slot ^ ((row >> 1) & 3)) * 8;
    lB[i] = (char*)&Bs[0][0][0] + c * 16;
  }

  f32x4 pa[2][2];
  #pragma unroll
  for (int i = 0; i < 2; i++) {
    pa[i][0] = *(const f32x4*)(gAs[i]);
    pa[i][1] = *(const f32x4*)(gAs[i] + 4);
  }
  #pragma unroll
  for (int i = 0; i < 2; i++) gload16(gB[i], lB[i]);
  #pragma unroll
  for (int i = 0; i < 2; i++)
    *(u16x8*)&As[0][arow_s[i]][aswz_s[i]] = cvt8(pa[i][0], pa[i][1]);

  int cur = 0;
  for (int kt = 0; kt < 512; kt += 32) {
    const int nb = cur ^ 1;
    if (kt < 480) {
      #pragma unroll
      for (int i = 0; i < 2; i++) {
        pa[i][0] = *(const f32x4*)(gAs[i] + kt + 32);
        pa[i][1] = *(const f32x4*)(gAs[i] + kt + 36);
      }
      #pragma unroll
      for (int i = 0; i < 2; i++) gload16(gB[i] + kt + 32, lB[i] + nb * 16384);
      asm volatile("s_waitcnt vmcnt(6) lgkmcnt(0)" ::: "memory");
    } else {
      asm volatile("s_waitcnt vmcnt(0) lgkmcnt(0)" ::: "memory");
    }
    __builtin_amdgcn_sched_barrier(0);
    __builtin_amdgcn_s_barrier();

    bf16x8 bv[4];
    #pragma unroll
    for (int nf = 0; nf < 4; nf++) {
      const int br = wc + nf * 16 + fr;
      bv[nf] = *(const bf16x8*)&Bs[cur][br][(fq ^ ((br >> 1) & 3)) * 8];
    }
    #pragma unroll
    for (int mf = 0; mf < 8; mf++) {
      const int ar = wr + mf * 16 + fr;
      bf16x8 av = *(const bf16x8*)&As[cur][ar][(fq ^ ((ar >> 1) & 3)) * 8];
      #pragma unroll
      for (int nf = 0; nf < 4; nf++)
        acc[mf][nf] = __builtin_amdgcn_mfma_f32_16x16x32_bf16(av, bv[nf], acc[mf][nf], 0, 0, 0);
    }

    if (kt < 480) {
      #pragma unroll
      for (int i = 0; i < 2; i++)
        *(u16x8*)&As[nb][arow_s[i]][aswz_s[i]] = cvt8(pa[i][0], pa[i][1]);
    }
    __builtin_amdgcn_s_barrier();
    cur = nb;
  }

  #pragma unroll
  for (int mf = 0; mf < 8; mf++)
    #pragma unroll
    for (int nf = 0; nf < 4; nf++)
      #pragma unroll
      for (int rr = 0; rr < 4; rr++) {
        const int m = m0 + wr + mf * 16 + fq * 4 + rr;
        const int n = n0 + wc + nf * 16 + fr;
        Y[(size_t)m * 512 + n] = f2bf(acc[mf][nf][rr]);
      }
}

// ---------------------------------------------------------------------------
// projv: vt[b][e][s] (unchanged from R6, with the 8192 stride fix)
// ---------------------------------------------------------------------------
__global__ __launch_bounds__(512, 2) void projv(
    const float* __restrict__ V, const unsigned short* __restrict__ wv,
    unsigned short* __restrict__ vt)
{
  __shared__ __align__(16) unsigned short As[2][128][32];
  __shared__ __align__(16) unsigned short Bs[2][256][32];

  const int tid = threadIdx.x;
  const int m0 = blockIdx.x * 128, n0 = blockIdx.y * 256, b = blockIdx.z;
  const int lane = tid & 63, wave = tid >> 6;
  const int wr = (wave >> 2) * 64, wc = (wave & 3) * 64;
  const int fr = lane & 15, fq = lane >> 4;

  f32x4 acc[4][4] = {};

  const int ar_s = tid >> 2, aslot = tid & 3;
  const unsigned short* gA = wv + (size_t)(m0 + ar_s) * 512 + (aslot ^ ((ar_s >> 1) & 3)) * 8;
  char* lA = (char*)&As[0][0][0] + tid * 16;

  int brow_s[2], bswz_s[2];
  const float* gBs[2];
  #pragma unroll
  for (int i = 0; i < 2; i++) {
    const int c = tid + 512 * i;
    brow_s[i] = c >> 2;
    bswz_s[i] = ((c & 3) ^ ((brow_s[i] >> 1) & 3)) * 8;
    gBs[i] = V + ((size_t)b * 1024 + n0 + brow_s[i]) * 512 + (c & 3) * 8;
  }

  f32x4 pb[2][2];
  #pragma unroll
  for (int i = 0; i < 2; i++) {
    pb[i][0] = *(const f32x4*)(gBs[i]);
    pb[i][1] = *(const f32x4*)(gBs[i] + 4);
  }
  gload16(gA, lA);
  #pragma unroll
  for (int i = 0; i < 2; i++)
    *(u16x8*)&Bs[0][brow_s[i]][bswz_s[i]] = cvt8(pb[i][0], pb[i][1]);

  int cur = 0;
  for (int kt = 0; kt < 512; kt += 32) {
    const int nb = cur ^ 1;
    if (kt < 480) {
      #pragma unroll
      for (int i = 0; i < 2; i++) {
        pb[i][0] = *(const f32x4*)(gBs[i] + kt + 32);
        pb[i][1] = *(const f32x4*)(gBs[i] + kt + 36);
      }
      gload16(gA + kt + 32, lA + nb * 8192);
      asm volatile("s_waitcnt vmcnt(5) lgkmcnt(0)" ::: "memory");
    } else {
      asm volatile("s_waitcnt vmcnt(0) lgkmcnt(0)" ::: "memory");
    }
    __builtin_amdgcn_sched_barrier(0);
    __builtin_amdgcn_s_barrier();

    bf16x8 av[4], bv[4];
    #pragma unroll
    for (int mf = 0; mf < 4; mf++) {
      const int ar = wr + mf * 16 + fr;
      av[mf] = *(const bf16x8*)&As[cur][ar][(fq ^ ((ar >> 1) & 3)) * 8];
    }
    #pragma unroll
    for (int nf = 0; nf < 4; nf++) {
      const int br = wc + nf * 16 + fr;
      bv[nf] = *(const bf16x8*)&Bs[cur][br][(fq ^ ((br >> 1) & 3)) * 8];
    }
    #pragma unroll
    for (int mf = 0; mf < 4; mf++)
      #pragma unroll
      for (int nf = 0; nf < 4; nf++)
        acc[mf][nf] = __builtin_amdgcn_mfma_f32_16x16x32_bf16(av[mf], bv[nf], acc[mf][nf], 0, 0, 0);

    if (kt < 480) {
      #pragma unroll
      for (int i = 0; i < 2; i++)
        *(u16x8*)&Bs[nb][brow_s[i]][bswz_s[i]] = cvt8(pb[i][0], pb[i][1]);
    }
    __builtin_amdgcn_s_barrier();
    cur = nb;
  }

  #pragma unroll
  for (int mf = 0; mf < 4; mf++)
    #pragma unroll
    for (int nf = 0; nf < 4; nf++)
      #pragma unroll
      for (int rr = 0; rr < 4; rr++) {
        const int e = m0 + wr + mf * 16 + fq * 4 + rr;
        const int s = n0 + wc + nf * 16 + fr;
        vt[((size_t)b * 512 + e) * 1024 + s] = f2bf(acc[mf][nf][rr]);
      }
}

// ---------------------------------------------------------------------------
// score256: s = (q k^T)/sqrt(512). Writes P''[b][m][k] = mask ? bf16(exp(s))
// : 0 (into the OUT region of d_out) + per-row partial exp-sums (sum over
// ALL k incl. masked — reference masks after softmax). No raw-score write.
// ---------------------------------------------------------------------------
__global__ __launch_bounds__(512, 2) void score256(
    const unsigned short* __restrict__ qb, const unsigned short* __restrict__ kb,
    const int* __restrict__ mask,
    unsigned short* __restrict__ P, float* __restrict__ partial)
{
  __shared__ __align__(16) unsigned short As[2][256][32];
  __shared__ __align__(16) unsigned short Bs[2][256][32];

  const int tid = threadIdx.x, bz = blockIdx.z;
  const int m0 = blockIdx.x * 256, n0 = blockIdx.y * 256;
  const int lane = tid & 63, wave = tid >> 6;
  const int wr = (wave >> 2) * 128, wc = (wave & 3) * 64;
  const int fr = lane & 15, fq = lane >> 4;

  f32x4 acc[8][4] = {};

  const unsigned short* gA[2]; char* lA[2];
  const unsigned short* gB[2]; char* lB[2];
  #pragma unroll
  for (int i = 0; i < 2; i++) {
    const int c = tid + 512 * i, row = c >> 2, slot = c & 3;
    const int sw = (slot ^ ((row >> 1) & 3)) * 8;
    gA[i] = qb + ((size_t)bz * 1024 + m0 + row) * 512 + sw;
    gB[i] = kb + ((size_t)bz * 1024 + n0 + row) * 512 + sw;
    lA[i] = (char*)&As[0][0][0] + c * 16;
    lB[i] = (char*)&Bs[0][0][0] + c * 16;
  }

  #pragma unroll
  for (int i = 0; i < 2; i++) { gload16(gA[i], lA[i]); gload16(gB[i], lB[i]); }

  int cur = 0;
  for (int kt = 0; kt < 512; kt += 32) {
    const int nb = cur ^ 1;
    if (kt < 480) {
      #pragma unroll
      for (int i = 0; i < 2; i++) {
        gload16(gA[i] + kt + 32, lA[i] + nb * 16384);
        gload16(gB[i] + kt + 32, lB[i] + nb * 16384);
      }
      asm volatile("s_waitcnt vmcnt(4) lgkmcnt(0)" ::: "memory");
    } else {
      asm volatile("s_waitcnt vmcnt(0) lgkmcnt(0)" ::: "memory");
    }
    __builtin_amdgcn_sched_barrier(0);
    __builtin_amdgcn_s_barrier();

    bf16x8 bv[4];
    #pragma unroll
    for (int nf = 0; nf < 4; nf++) {
      const int br = wc + nf * 16 + fr;
      bv[nf] = *(const bf16x8*)&Bs[cur][br][(fq ^ ((br >> 1) & 3)) * 8];
    }
    #pragma unroll
    for (int mf = 0; mf < 8; mf++) {
      const int ar = wr + mf * 16 + fr;
      bf16x8 av = *(const bf16x8*)&As[cur][ar][(fq ^ ((ar >> 1) & 3)) * 8];
      #pragma unroll
      for (int nf = 0; nf < 4; nf++)
        acc[mf][nf] = __builtin_amdgcn_mfma_f32_16x16x32_bf16(av, bv[nf], acc[mf][nf], 0, 0, 0);
    }
    __builtin_amdgcn_s_barrier();
    cur = nb;
  }

  // epilogue: P'' = mask ? bf16(exp(s)) : 0 ; partial rowsum of exp(s)
  int mcol[4];
  #pragma unroll
  for (int nf = 0; nf < 4; nf++)
    mcol[nf] = mask[bz * 1024 + n0 + wc + nf * 16 + fr];

  unsigned short* Pb = P + ((size_t)bz << 20);
  const int slot = blockIdx.y * 4 + (wave & 3);
  #pragma unroll
  for (int mf = 0; mf < 8; mf++) {
    #pragma unroll
    for (int rr = 0; rr < 4; rr++) {
      const int m = m0 + wr + mf * 16 + fq * 4 + rr;
      float e = 0.f;
      #pragma unroll
      for (int nf = 0; nf < 4; nf++) {
        const float ev = __expf(acc[mf][nf][rr] * SCALE_F);
        e += ev;
        Pb[(size_t)m * 1024 + n0 + wc + nf * 16 + fr] =
            mcol[nf] ? f2bf(ev) : (unsigned short)0;
      }
      e += __shfl_xor(e, 1); e += __shfl_xor(e, 2);
      e += __shfl_xor(e, 4); e += __shfl_xor(e, 8);
      if (fr == 0)
        partial[(size_t)slot * 16384 + bz * 1024 + m] = e;
    }
  }
}

// ---------------------------------------------------------------------------
// rs_inv: inv[i] = 1 / sum_{s<16} partial[s][i]
// ---------------------------------------------------------------------------
__global__ __launch_bounds__(256) void rs_inv(
    const float* __restrict__ partial, float* __restrict__ inv)
{
  const int i = blockIdx.x * 256 + threadIdx.x;
  float s = 0.f;
  #pragma unroll
  for (int p = 0; p < 16; p++) s += partial[(size_t)p * 16384 + i];
  inv[i] = 1.0f / s;
}

// ---------------------------------------------------------------------------
// mvsum_k: mvsum[b][e] = sum_{s: mask==0} vt[b][e][s]. One wave per (b,e).
// ---------------------------------------------------------------------------
__global__ __launch_bounds__(256) void mvsum_k(
    const unsigned short* __restrict__ vt, const int* __restrict__ mask,
    float* __restrict__ mvsum)
{
  const int row = blockIdx.x * 4 + (threadIdx.x >> 6);   // 0..8191 = b*512+e
  const int b = row >> 9;
  const int lane = threadIdx.x & 63;
  const unsigned short* vr = vt + (size_t)row * 1024 + lane * 16;
  const int* mr = mask + b * 1024 + lane * 16;
  u16x8 v0 = *(const u16x8*)(vr);
  u16x8 v1 = *(const u16x8*)(vr + 8);
  float s = 0.f;
  #pragma unroll
  for (int j = 0; j < 8; j++) {
    if (!mr[j])     s += bf2f(v0[j]);
    if (!mr[8 + j]) s += bf2f(v1[j]);
  }
  #pragma unroll
  for (int o = 32; o > 0; o >>= 1) s += __shfl_xor(s, o);
  if (lane == 0) mvsum[row] = s;
}

// ---------------------------------------------------------------------------
// attn_write: attn[b][m][k] = mask ? f32(P''[m][k]) * inv[b,m] : -1e9
// pure streaming; 8 elems/thread.
// ---------------------------------------------------------------------------
__global__ __launch_bounds__(256) void attn_write(
    const unsigned short* __restrict__ P, const float* __restrict__ inv,
    const int* __restrict__ mask, float* __restrict__ attn)
{
  const size_t base = ((size_t)blockIdx.x * 256 + threadIdx.x) * 8;
  const int row = (int)(base >> 10);          // global q-row 0..16383
  const int b = row >> 10;
  const int k0 = (int)(base & 1023);
  const u16x8 p8 = *(const u16x8*)(P + base);
  const float iv = inv[row];
  const int* mr = mask + b * 1024 + k0;
  const i32x4 ma = *(const i32x4*)(mr);
  const i32x4 mb = *(const i32x4*)(mr + 4);
  f32x4 o0, o1;
  o0[0] = ma[0] ? bf2f(p8[0]) * iv : NEG_BIG_F;
  o0[1] = ma[1] ? bf2f(p8[1]) * iv : NEG_BIG_F;
  o0[2] = ma[2] ? bf2f(p8[2]) * iv : NEG_BIG_F;
  o0[3] = ma[3] ? bf2f(p8[3]) * iv : NEG_BIG_F;
  o1[0] = mb[0] ? bf2f(p8[4]) * iv : NEG_BIG_F;
  o1[1] = mb[1] ? bf2f(p8[5]) * iv : NEG_BIG_F;
  o1[2] = mb[2] ? bf2f(p8[6]) * iv : NEG_BIG_F;
  o1[3] = mb[3] ? bf2f(p8[7]) * iv : NEG_BIG_F;
  *(f32x4*)(attn + base) = o0;
  *(f32x4*)(attn + base + 4) = o1;
}

// ---------------------------------------------------------------------------
// pv_gemm: pure bf16 GEMM. out[b][m][e] = inv[m]*(P''·vt^T) - 1e9*mvsum[b][e].
// 64(m) x 512(e) tile, K=1024, BK=32, 512 thr = 8 waves (wave tile 64x64).
// Both operands via global_load_lds + 4-slot XOR swizzle; counted vmcnt
// (5 for waves 0-3 which also stage A, else 4); two-barrier loop.
// Epilogue clobbers P'' rows m0..m0+63 (this block's exclusive rows) — safe,
// attn_write ran before this kernel.
// ---------------------------------------------------------------------------
__global__ __launch_bounds__(512) void pv_gemm(
    const unsigned short* __restrict__ P, const unsigned short* __restrict__ vt,
    const float* __restrict__ inv, const float* __restrict__ mvsum,
    float* __restrict__ out)
{
  __shared__ __align__(16) unsigned short As[2][64][32];   // 8 KB
  __shared__ __align__(16) unsigned short Bs[2][512][32];  // 64 KB

  const int tid = threadIdx.x;
  const int bz = blockIdx.z, m0 = blockIdx.x * 64;
  const int lane = tid & 63, wave = tid >> 6;
  const int n0 = wave * 64;
  const int fr = lane & 15, fq = lane >> 4;

  f32x4 acc[4][4] = {};

  // A: 256 chunks -> waves 0-3 (1/thread). row = c>>2, slot = c&3.
  const unsigned short* gA = nullptr; char* lA = nullptr;
  if (tid < 256) {
    const int row = tid >> 2, slot = tid & 3;
    gA = P + ((size_t)bz << 20) + (size_t)(m0 + row) * 1024 + (slot ^ ((row >> 1) & 3)) * 8;
    lA = (char*)&As[0][0][0] + tid * 16;
  }
  // B: 2048 chunks -> 4/thread
  const unsigned short* gB[4]; char* lB[4];
  #pragma unroll
  for (int i = 0; i < 4; i++) {
    const int c = tid + 512 * i, row = c >> 2, slot = c & 3;
    gB[i] = vt + ((size_t)bz * 512 + row) * 1024 + (slot ^ ((row >> 1) & 3)) * 8;
    lB[i] = (char*)&Bs[0][0][0] + c * 16;
  }

  // prologue: buf 0, kt = 0
  if (tid < 256) gload16(gA, lA);
  #pragma unroll
  for (int i = 0; i < 4; i++) gload16(gB[i], lB[i]);

  int cur = 0;
  for (int t = 0; t < 32; t++) {
    const int nb = cur ^ 1;
    const int kt = t * 32;
    if (t < 31) {
      if (tid < 256) gload16(gA + kt + 32, lA + nb * 4096);      // 64*32*2
      #pragma unroll
      for (int i = 0; i < 4; i++) gload16(gB[i] + kt + 32, lB[i] + nb * 32768);  // 512*32*2
      if (wave < 4) asm volatile("s_waitcnt vmcnt(5) lgkmcnt(0)" ::: "memory");
      else          asm volatile("s_waitcnt vmcnt(4) lgkmcnt(0)" ::: "memory");
    } else {
      asm volatile("s_waitcnt vmcnt(0) lgkmcnt(0)" ::: "memory");
    }
    __builtin_amdgcn_sched_barrier(0);
    __builtin_amdgcn_s_barrier();

    bf16x8 af[4], bv[4];
    #pragma unroll
    for (int mf = 0; mf < 4; mf++) {
      const int ar = mf * 16 + fr;
      af[mf] = *(const bf16x8*)&As[cur][ar][(fq ^ ((ar >> 1) & 3)) * 8];
    }
    #pragma unroll
    for (int nf = 0; nf < 4; nf++) {
      const int br = n0 + nf * 16 + fr;
      bv[nf] = *(const bf16x8*)&Bs[cur][br][(fq ^ ((br >> 1) & 3)) * 8];
    }
    #pragma unroll
    for (int mf = 0; mf < 4; mf++)
      #pragma unroll
      for (int nf = 0; nf < 4; nf++)
        acc[mf][nf] = __builtin_amdgcn_mfma_f32_16x16x32_bf16(af[mf], bv[nf], acc[mf][nf], 0, 0, 0);
    __builtin_amdgcn_s_barrier();
    cur = nb;
  }

  float mvv[4];
  #pragma unroll
  for (int nf = 0; nf < 4; nf++)
    mvv[nf] = mvsum[bz * 512 + n0 + nf * 16 + fr];
  #pragma unroll
  for (int mf = 0; mf < 4; mf++)
    #pragma unroll
    for (int rr = 0; rr < 4; rr++) {
      const int m = m0 + mf * 16 + fq * 4 + rr;
      const float iv = inv[bz * 1024 + m];
      #pragma unroll
      for (int nf = 0; nf < 4; nf++)
        out[((size_t)bz * 1024 + m) * 512 + n0 + nf * 16 + fr] =
            iv * acc[mf][nf][rr] + NEG_BIG_F * mvv[nf];
    }
}

// ---------------------------------------------------------------------------
extern "C" void kernel_launch(void* const* d_in, const int* in_sizes, int n_in,
                              void* d_out, int out_size, void* d_ws, size_t ws_size,
                              hipStream_t stream)
{
  const float* Q  = (const float*)d_in[0];
  const float* Kx = (const float*)d_in[1];
  const float* V  = (const float*)d_in[2];
  const float* WQ = (const float*)d_in[3];
  const float* WK = (const float*)d_in[4];
  const float* WV = (const float*)d_in[5];
  const int* mask = (const int*)d_in[6];

  const int B = 16, S = 1024, D = 512;
  float* out_f  = (float*)d_out;                      // B*S*D fp32 (final out)
  float* attn_f = out_f + (size_t)B * S * D;          // B*S*S fp32 (final attn)
  unsigned short* Pbuf = (unsigned short*)d_out;      // P'' bf16 ALIASES out
                                                      // region (33.5 MB exact);
                                                      // clobbered by pv_gemm
                                                      // after attn_write read it.

  // ws: qb | kb | vt (8.39M ushorts each) | wb (0.79M) | partial | inv | mvsum
  unsigned short* qb = (unsigned short*)d_ws;
  unsigned short* kb = qb + (size_t)B * S * D;
  unsigned short* vt = kb + (size_t)B * S * D;
  unsigned short* wb = vt + (size_t)B * S * D;
  float* partial = (float*)(wb + 786432);             // 16 x 16384 f32
  float* inv = partial + 262144;                      // 16384 f32
  float* mvsum = inv + 16384;                         // 16 x 512 f32

  cvtW<<<dim3(128, 1, 3), 256, 0, stream>>>(WQ, WK, WV, wb);
  projqk<<<dim3(64, 2, 2), 512, 0, stream>>>(Q, Kx, wb, qb, kb);
  projv<<<dim3(4, 4, 16), 512, 0, stream>>>(V, wb + 524288, vt);
  score256<<<dim3(4, 4, 16), 512, 0, stream>>>(qb, kb, mask, Pbuf, partial);
  rs_inv<<<dim3(64), 256, 0, stream>>>(partial, inv);
  mvsum_k<<<dim3(2048), 256, 0, stream>>>(vt, mask, mvsum);
  attn_write<<<dim3(8192), 256, 0, stream>>>(Pbuf, inv, mask, attn_f);
  pv_gemm<<<dim3(16, 1, 16), 512, 0, stream>>>(Pbuf, vt, inv, mvsum, out_f);
}

// Round 8
// 149.144 us; speedup vs baseline: 1.1141x; 1.1141x over previous
//
#include <hip/hip_runtime.h>
#include <hip/hip_bf16.h>

typedef float f32x4 __attribute__((ext_vector_type(4)));
typedef __bf16 bf16x8 __attribute__((ext_vector_type(8)));
typedef unsigned short u16x8 __attribute__((ext_vector_type(8)));
typedef int i32x4 __attribute__((ext_vector_type(4)));

#define NEG_BIG_F (-1000000000.0f)
#define SCALE_F 0.044194173824159216f

__device__ __forceinline__ unsigned short f2bf(float f) {
  unsigned int u = __float_as_uint(f);
  u += 0x7FFFu + ((u >> 16) & 1u);   // round-to-nearest-even
  return (unsigned short)(u >> 16);
}

__device__ __forceinline__ float bf2f(unsigned short h) {
  return __uint_as_float((unsigned int)h << 16);
}

__device__ __forceinline__ u16x8 cvt8(f32x4 a, f32x4 b) {
  u16x8 r;
  r[0] = f2bf(a[0]); r[1] = f2bf(a[1]); r[2] = f2bf(a[2]); r[3] = f2bf(a[3]);
  r[4] = f2bf(b[0]); r[5] = f2bf(b[1]); r[6] = f2bf(b[2]); r[7] = f2bf(b[3]);
  return r;
}

__device__ __forceinline__ void gload16(const void* g, char* l) {
  __builtin_amdgcn_global_load_lds(
      (const __attribute__((address_space(1))) unsigned int*)g,
      (__attribute__((address_space(3))) unsigned int*)l, 16, 0, 0);
}

// ---------------------------------------------------------------------------
// cvtW: three 512x512 fp32 weight matrices -> bf16
// ---------------------------------------------------------------------------
__global__ __launch_bounds__(256) void cvtW(
    const float* __restrict__ w0, const float* __restrict__ w1,
    const float* __restrict__ w2, unsigned short* __restrict__ out)
{
  const float* src = blockIdx.z == 0 ? w0 : (blockIdx.z == 1 ? w1 : w2);
  unsigned short* dst = out + (size_t)blockIdx.z * 262144;
  const int i = (blockIdx.x * 256 + threadIdx.x) * 8;
  f32x4 a = *(const f32x4*)(src + i);
  f32x4 b = *(const f32x4*)(src + i + 4);
  *(u16x8*)&dst[i] = cvt8(a, b);
}

// ---------------------------------------------------------------------------
// proj_all: blocks 0-255 = projqk (z=bid>>7: 0 Q,1 K; 256x256 tile),
//           blocks 256-511 = projv (vt = WV·V^T; 128x256 tile).
// Both bodies verbatim from R6/R7 (proven); LDS pool aliased per branch.
// ---------------------------------------------------------------------------
__global__ __launch_bounds__(512, 2) void proj_all(
    const float* __restrict__ Q, const float* __restrict__ Kx,
    const float* __restrict__ V, const unsigned short* __restrict__ wb,
    unsigned short* __restrict__ qb, unsigned short* __restrict__ kb,
    unsigned short* __restrict__ vt)
{
  __shared__ __align__(16) unsigned short lds[32768];   // 64 KB pool

  const int bid = blockIdx.x;
  const int tid = threadIdx.x;
  const int lane = tid & 63, wave = tid >> 6;
  const int fr = lane & 15, fq = lane >> 4;

  if (bid < 256) {
    // ---------------- projqk ----------------
    const int z = bid >> 7, rem = bid & 127;
    const float* X = z ? Kx : Q;
    const unsigned short* W = wb + (size_t)z * 262144;
    unsigned short* Y = z ? kb : qb;
    const int m0 = (rem & 63) * 256, n0 = (rem >> 6) * 256;
    const int wr = (wave >> 2) * 128, wc = (wave & 3) * 64;

    // As[2][256][32] at lds, Bs[2][256][32] at lds+16384
    unsigned short (*As)[256][32] = (unsigned short (*)[256][32])lds;
    unsigned short (*Bs)[256][32] = (unsigned short (*)[256][32])(lds + 16384);

    f32x4 acc[8][4] = {};

    int arow_s[2], aswz_s[2];
    const float* gAs[2];
    #pragma unroll
    for (int i = 0; i < 2; i++) {
      const int c = tid + 512 * i;
      arow_s[i] = c >> 2;
      aswz_s[i] = ((c & 3) ^ ((arow_s[i] >> 1) & 3)) * 8;
      gAs[i] = X + (size_t)(m0 + arow_s[i]) * 512 + (c & 3) * 8;
    }
    const unsigned short* gB[2]; char* lB[2];
    #pragma unroll
    for (int i = 0; i < 2; i++) {
      const int c = tid + 512 * i, row = c >> 2, slot = c & 3;
      gB[i] = W + (size_t)(n0 + row) * 512 + (slot ^ ((row >> 1) & 3)) * 8;
      lB[i] = (char*)(lds + 16384) + c * 16;
    }

    f32x4 pa[2][2];
    #pragma unroll
    for (int i = 0; i < 2; i++) {
      pa[i][0] = *(const f32x4*)(gAs[i]);
      pa[i][1] = *(const f32x4*)(gAs[i] + 4);
    }
    #pragma unroll
    for (int i = 0; i < 2; i++) gload16(gB[i], lB[i]);
    #pragma unroll
    for (int i = 0; i < 2; i++)
      *(u16x8*)&As[0][arow_s[i]][aswz_s[i]] = cvt8(pa[i][0], pa[i][1]);

    int cur = 0;
    for (int kt = 0; kt < 512; kt += 32) {
      const int nb = cur ^ 1;
      if (kt < 480) {
        #pragma unroll
        for (int i = 0; i < 2; i++) {
          pa[i][0] = *(const f32x4*)(gAs[i] + kt + 32);
          pa[i][1] = *(const f32x4*)(gAs[i] + kt + 36);
        }
        #pragma unroll
        for (int i = 0; i < 2; i++) gload16(gB[i] + kt + 32, lB[i] + nb * 16384);
        asm volatile("s_waitcnt vmcnt(6) lgkmcnt(0)" ::: "memory");
      } else {
        asm volatile("s_waitcnt vmcnt(0) lgkmcnt(0)" ::: "memory");
      }
      __builtin_amdgcn_sched_barrier(0);
      __builtin_amdgcn_s_barrier();

      bf16x8 bv[4];
      #pragma unroll
      for (int nf = 0; nf < 4; nf++) {
        const int br = wc + nf * 16 + fr;
        bv[nf] = *(const bf16x8*)&Bs[cur][br][(fq ^ ((br >> 1) & 3)) * 8];
      }
      #pragma unroll
      for (int mf = 0; mf < 8; mf++) {
        const int ar = wr + mf * 16 + fr;
        bf16x8 av = *(const bf16x8*)&As[cur][ar][(fq ^ ((ar >> 1) & 3)) * 8];
        #pragma unroll
        for (int nf = 0; nf < 4; nf++)
          acc[mf][nf] = __builtin_amdgcn_mfma_f32_16x16x32_bf16(av, bv[nf], acc[mf][nf], 0, 0, 0);
      }

      if (kt < 480) {
        #pragma unroll
        for (int i = 0; i < 2; i++)
          *(u16x8*)&As[nb][arow_s[i]][aswz_s[i]] = cvt8(pa[i][0], pa[i][1]);
      }
      __builtin_amdgcn_s_barrier();
      cur = nb;
    }

    #pragma unroll
    for (int mf = 0; mf < 8; mf++)
      #pragma unroll
      for (int nf = 0; nf < 4; nf++)
        #pragma unroll
        for (int rr = 0; rr < 4; rr++) {
          const int m = m0 + wr + mf * 16 + fq * 4 + rr;
          const int n = n0 + wc + nf * 16 + fr;
          Y[(size_t)m * 512 + n] = f2bf(acc[mf][nf][rr]);
        }
  } else {
    // ---------------- projv ----------------
    const int c0 = bid - 256;
    const int m0 = (c0 & 3) * 128, n0 = ((c0 >> 2) & 3) * 256, b = c0 >> 4;
    const int wr = (wave >> 2) * 64, wc = (wave & 3) * 64;
    const unsigned short* wv = wb + 524288;

    // As[2][128][32] at lds, Bs[2][256][32] at lds+8192
    unsigned short (*As)[128][32] = (unsigned short (*)[128][32])lds;
    unsigned short (*Bs)[256][32] = (unsigned short (*)[256][32])(lds + 8192);

    f32x4 acc[4][4] = {};

    const int ar_s = tid >> 2, aslot = tid & 3;
    const unsigned short* gA = wv + (size_t)(m0 + ar_s) * 512 + (aslot ^ ((ar_s >> 1) & 3)) * 8;
    char* lA = (char*)lds + tid * 16;

    int brow_s[2], bswz_s[2];
    const float* gBs[2];
    #pragma unroll
    for (int i = 0; i < 2; i++) {
      const int c = tid + 512 * i;
      brow_s[i] = c >> 2;
      bswz_s[i] = ((c & 3) ^ ((brow_s[i] >> 1) & 3)) * 8;
      gBs[i] = V + ((size_t)b * 1024 + n0 + brow_s[i]) * 512 + (c & 3) * 8;
    }

    f32x4 pb[2][2];
    #pragma unroll
    for (int i = 0; i < 2; i++) {
      pb[i][0] = *(const f32x4*)(gBs[i]);
      pb[i][1] = *(const f32x4*)(gBs[i] + 4);
    }
    gload16(gA, lA);
    #pragma unroll
    for (int i = 0; i < 2; i++)
      *(u16x8*)&Bs[0][brow_s[i]][bswz_s[i]] = cvt8(pb[i][0], pb[i][1]);

    int cur = 0;
    for (int kt = 0; kt < 512; kt += 32) {
      const int nb = cur ^ 1;
      if (kt < 480) {
        #pragma unroll
        for (int i = 0; i < 2; i++) {
          pb[i][0] = *(const f32x4*)(gBs[i] + kt + 32);
          pb[i][1] = *(const f32x4*)(gBs[i] + kt + 36);
        }
        gload16(gA + kt + 32, lA + nb * 8192);
        asm volatile("s_waitcnt vmcnt(5) lgkmcnt(0)" ::: "memory");
      } else {
        asm volatile("s_waitcnt vmcnt(0) lgkmcnt(0)" ::: "memory");
      }
      __builtin_amdgcn_sched_barrier(0);
      __builtin_amdgcn_s_barrier();

      bf16x8 av[4], bv[4];
      #pragma unroll
      for (int mf = 0; mf < 4; mf++) {
        const int ar = wr + mf * 16 + fr;
        av[mf] = *(const bf16x8*)&As[cur][ar][(fq ^ ((ar >> 1) & 3)) * 8];
      }
      #pragma unroll
      for (int nf = 0; nf < 4; nf++) {
        const int br = wc + nf * 16 + fr;
        bv[nf] = *(const bf16x8*)&Bs[cur][br][(fq ^ ((br >> 1) & 3)) * 8];
      }
      #pragma unroll
      for (int mf = 0; mf < 4; mf++)
        #pragma unroll
        for (int nf = 0; nf < 4; nf++)
          acc[mf][nf] = __builtin_amdgcn_mfma_f32_16x16x32_bf16(av[mf], bv[nf], acc[mf][nf], 0, 0, 0);

      if (kt < 480) {
        #pragma unroll
        for (int i = 0; i < 2; i++)
          *(u16x8*)&Bs[nb][brow_s[i]][bswz_s[i]] = cvt8(pb[i][0], pb[i][1]);
      }
      __builtin_amdgcn_s_barrier();
      cur = nb;
    }

    #pragma unroll
    for (int mf = 0; mf < 4; mf++)
      #pragma unroll
      for (int nf = 0; nf < 4; nf++)
        #pragma unroll
        for (int rr = 0; rr < 4; rr++) {
          const int e = m0 + wr + mf * 16 + fq * 4 + rr;
          const int s = n0 + wc + nf * 16 + fr;
          vt[((size_t)b * 512 + e) * 1024 + s] = f2bf(acc[mf][nf][rr]);
        }
  }
}

// ---------------------------------------------------------------------------
// score256: s = (q k^T)/sqrt(512). Writes P''[b][m][k] = mask ? bf16(exp(s))
// : 0 (into the OUT region of d_out) + per-row partial exp-sums.
// (unchanged from R7 — proven)
// ---------------------------------------------------------------------------
__global__ __launch_bounds__(512, 2) void score256(
    const unsigned short* __restrict__ qb, const unsigned short* __restrict__ kb,
    const int* __restrict__ mask,
    unsigned short* __restrict__ P, float* __restrict__ partial)
{
  __shared__ __align__(16) unsigned short As[2][256][32];
  __shared__ __align__(16) unsigned short Bs[2][256][32];

  const int tid = threadIdx.x, bz = blockIdx.z;
  const int m0 = blockIdx.x * 256, n0 = blockIdx.y * 256;
  const int lane = tid & 63, wave = tid >> 6;
  const int wr = (wave >> 2) * 128, wc = (wave & 3) * 64;
  const int fr = lane & 15, fq = lane >> 4;

  f32x4 acc[8][4] = {};

  const unsigned short* gA[2]; char* lA[2];
  const unsigned short* gB[2]; char* lB[2];
  #pragma unroll
  for (int i = 0; i < 2; i++) {
    const int c = tid + 512 * i, row = c >> 2, slot = c & 3;
    const int sw = (slot ^ ((row >> 1) & 3)) * 8;
    gA[i] = qb + ((size_t)bz * 1024 + m0 + row) * 512 + sw;
    gB[i] = kb + ((size_t)bz * 1024 + n0 + row) * 512 + sw;
    lA[i] = (char*)&As[0][0][0] + c * 16;
    lB[i] = (char*)&Bs[0][0][0] + c * 16;
  }

  #pragma unroll
  for (int i = 0; i < 2; i++) { gload16(gA[i], lA[i]); gload16(gB[i], lB[i]); }

  int cur = 0;
  for (int kt = 0; kt < 512; kt += 32) {
    const int nb = cur ^ 1;
    if (kt < 480) {
      #pragma unroll
      for (int i = 0; i < 2; i++) {
        gload16(gA[i] + kt + 32, lA[i] + nb * 16384);
        gload16(gB[i] + kt + 32, lB[i] + nb * 16384);
      }
      asm volatile("s_waitcnt vmcnt(4) lgkmcnt(0)" ::: "memory");
    } else {
      asm volatile("s_waitcnt vmcnt(0) lgkmcnt(0)" ::: "memory");
    }
    __builtin_amdgcn_sched_barrier(0);
    __builtin_amdgcn_s_barrier();

    bf16x8 bv[4];
    #pragma unroll
    for (int nf = 0; nf < 4; nf++) {
      const int br = wc + nf * 16 + fr;
      bv[nf] = *(const bf16x8*)&Bs[cur][br][(fq ^ ((br >> 1) & 3)) * 8];
    }
    #pragma unroll
    for (int mf = 0; mf < 8; mf++) {
      const int ar = wr + mf * 16 + fr;
      bf16x8 av = *(const bf16x8*)&As[cur][ar][(fq ^ ((ar >> 1) & 3)) * 8];
      #pragma unroll
      for (int nf = 0; nf < 4; nf++)
        acc[mf][nf] = __builtin_amdgcn_mfma_f32_16x16x32_bf16(av, bv[nf], acc[mf][nf], 0, 0, 0);
    }
    __builtin_amdgcn_s_barrier();
    cur = nb;
  }

  int mcol[4];
  #pragma unroll
  for (int nf = 0; nf < 4; nf++)
    mcol[nf] = mask[bz * 1024 + n0 + wc + nf * 16 + fr];

  unsigned short* Pb = P + ((size_t)bz << 20);
  const int slot = blockIdx.y * 4 + (wave & 3);
  #pragma unroll
  for (int mf = 0; mf < 8; mf++) {
    #pragma unroll
    for (int rr = 0; rr < 4; rr++) {
      const int m = m0 + wr + mf * 16 + fq * 4 + rr;
      float e = 0.f;
      #pragma unroll
      for (int nf = 0; nf < 4; nf++) {
        const float ev = __expf(acc[mf][nf][rr] * SCALE_F);
        e += ev;
        Pb[(size_t)m * 1024 + n0 + wc + nf * 16 + fr] =
            mcol[nf] ? f2bf(ev) : (unsigned short)0;
      }
      e += __shfl_xor(e, 1); e += __shfl_xor(e, 2);
      e += __shfl_xor(e, 4); e += __shfl_xor(e, 8);
      if (fr == 0)
        partial[(size_t)slot * 16384 + bz * 1024 + m] = e;
    }
  }
}

// ---------------------------------------------------------------------------
// mv_attn: blocks 0-2047 = mvsum (mvsum[b][e] = sum_{mask==0} vt[b][e][s]);
//          blocks 2048-10239 = attn_write with inv recomputed from partial.
// ---------------------------------------------------------------------------
__global__ __launch_bounds__(256) void mv_attn(
    const unsigned short* __restrict__ vt, const unsigned short* __restrict__ P,
    const float* __restrict__ partial, const int* __restrict__ mask,
    float* __restrict__ mvsum, float* __restrict__ attn)
{
  const int bid = blockIdx.x;
  const int tid = threadIdx.x;
  if (bid < 2048) {
    const int row = bid * 4 + (tid >> 6);   // 0..8191 = b*512+e
    const int b = row >> 9;
    const int lane = tid & 63;
    const unsigned short* vr = vt + (size_t)row * 1024 + lane * 16;
    const int* mr = mask + b * 1024 + lane * 16;
    u16x8 v0 = *(const u16x8*)(vr);
    u16x8 v1 = *(const u16x8*)(vr + 8);
    float s = 0.f;
    #pragma unroll
    for (int j = 0; j < 8; j++) {
      if (!mr[j])     s += bf2f(v0[j]);
      if (!mr[8 + j]) s += bf2f(v1[j]);
    }
    #pragma unroll
    for (int o = 32; o > 0; o >>= 1) s += __shfl_xor(s, o);
    if (lane == 0) mvsum[row] = s;
  } else {
    const int ab = bid - 2048;              // 0..8191, covers 2 q-rows each
    __shared__ float s_inv[2];
    const int row0 = ab * 2;
    if (tid < 2) {
      float s = 0.f;
      #pragma unroll
      for (int p = 0; p < 16; p++) s += partial[(size_t)p * 16384 + row0 + tid];
      s_inv[tid] = 1.0f / s;
    }
    __syncthreads();
    const size_t base = (size_t)ab * 2048 + tid * 8;
    const int b = (int)(base >> 20);
    const int k0 = (int)(base & 1023);
    const u16x8 p8 = *(const u16x8*)(P + base);
    const float iv = s_inv[tid >> 7];
    const int* mr = mask + b * 1024 + k0;
    const i32x4 ma = *(const i32x4*)(mr);
    const i32x4 mb = *(const i32x4*)(mr + 4);
    f32x4 o0, o1;
    o0[0] = ma[0] ? bf2f(p8[0]) * iv : NEG_BIG_F;
    o0[1] = ma[1] ? bf2f(p8[1]) * iv : NEG_BIG_F;
    o0[2] = ma[2] ? bf2f(p8[2]) * iv : NEG_BIG_F;
    o0[3] = ma[3] ? bf2f(p8[3]) * iv : NEG_BIG_F;
    o1[0] = mb[0] ? bf2f(p8[4]) * iv : NEG_BIG_F;
    o1[1] = mb[1] ? bf2f(p8[5]) * iv : NEG_BIG_F;
    o1[2] = mb[2] ? bf2f(p8[6]) * iv : NEG_BIG_F;
    o1[3] = mb[3] ? bf2f(p8[7]) * iv : NEG_BIG_F;
    *(f32x4*)(attn + base) = o0;
    *(f32x4*)(attn + base + 4) = o1;
  }
}

// ---------------------------------------------------------------------------
// pv_gemm: out[b][m][e] = inv[m]*(P''·vt^T) - 1e9*mvsum[b][e]. inv computed
// in prologue from partial (LDS). Otherwise unchanged from R7 (proven).
// ---------------------------------------------------------------------------
__global__ __launch_bounds__(512) void pv_gemm(
    const unsigned short* __restrict__ P, const unsigned short* __restrict__ vt,
    const float* __restrict__ partial, const float* __restrict__ mvsum,
    float* __restrict__ out)
{
  __shared__ __align__(16) unsigned short As[2][64][32];   // 8 KB
  __shared__ __align__(16) unsigned short Bs[2][512][32];  // 64 KB
  __shared__ float inv_l[64];

  const int tid = threadIdx.x;
  const int bz = blockIdx.z, m0 = blockIdx.x * 64;
  const int lane = tid & 63, wave = tid >> 6;
  const int n0 = wave * 64;
  const int fr = lane & 15, fq = lane >> 4;

  f32x4 acc[4][4] = {};

  if (tid < 64) {
    float s = 0.f;
    #pragma unroll
    for (int p = 0; p < 16; p++) s += partial[(size_t)p * 16384 + bz * 1024 + m0 + tid];
    inv_l[tid] = 1.0f / s;
  }

  const unsigned short* gA = nullptr; char* lA = nullptr;
  if (tid < 256) {
    const int row = tid >> 2, slot = tid & 3;
    gA = P + ((size_t)bz << 20) + (size_t)(m0 + row) * 1024 + (slot ^ ((row >> 1) & 3)) * 8;
    lA = (char*)&As[0][0][0] + tid * 16;
  }
  const unsigned short* gB[4]; char* lB[4];
  #pragma unroll
  for (int i = 0; i < 4; i++) {
    const int c = tid + 512 * i, row = c >> 2, slot = c & 3;
    gB[i] = vt + ((size_t)bz * 512 + row) * 1024 + (slot ^ ((row >> 1) & 3)) * 8;
    lB[i] = (char*)&Bs[0][0][0] + c * 16;
  }

  if (tid < 256) gload16(gA, lA);
  #pragma unroll
  for (int i = 0; i < 4; i++) gload16(gB[i], lB[i]);

  int cur = 0;
  for (int t = 0; t < 32; t++) {
    const int nb = cur ^ 1;
    const int kt = t * 32;
    if (t < 31) {
      if (tid < 256) gload16(gA + kt + 32, lA + nb * 4096);
      #pragma unroll
      for (int i = 0; i < 4; i++) gload16(gB[i] + kt + 32, lB[i] + nb * 32768);
      if (wave < 4) asm volatile("s_waitcnt vmcnt(5) lgkmcnt(0)" ::: "memory");
      else          asm volatile("s_waitcnt vmcnt(4) lgkmcnt(0)" ::: "memory");
    } else {
      asm volatile("s_waitcnt vmcnt(0) lgkmcnt(0)" ::: "memory");
    }
    __builtin_amdgcn_sched_barrier(0);
    __builtin_amdgcn_s_barrier();

    bf16x8 af[4], bv[4];
    #pragma unroll
    for (int mf = 0; mf < 4; mf++) {
      const int ar = mf * 16 + fr;
      af[mf] = *(const bf16x8*)&As[cur][ar][(fq ^ ((ar >> 1) & 3)) * 8];
    }
    #pragma unroll
    for (int nf = 0; nf < 4; nf++) {
      const int br = n0 + nf * 16 + fr;
      bv[nf] = *(const bf16x8*)&Bs[cur][br][(fq ^ ((br >> 1) & 3)) * 8];
    }
    #pragma unroll
    for (int mf = 0; mf < 4; mf++)
      #pragma unroll
      for (int nf = 0; nf < 4; nf++)
        acc[mf][nf] = __builtin_amdgcn_mfma_f32_16x16x32_bf16(af[mf], bv[nf], acc[mf][nf], 0, 0, 0);
    __builtin_amdgcn_s_barrier();
    cur = nb;
  }

  float mvv[4];
  #pragma unroll
  for (int nf = 0; nf < 4; nf++)
    mvv[nf] = mvsum[bz * 512 + n0 + nf * 16 + fr];
  #pragma unroll
  for (int mf = 0; mf < 4; mf++)
    #pragma unroll
    for (int rr = 0; rr < 4; rr++) {
      const int m = m0 + mf * 16 + fq * 4 + rr;
      const float iv = inv_l[mf * 16 + fq * 4 + rr];
      #pragma unroll
      for (int nf = 0; nf < 4; nf++)
        out[((size_t)bz * 1024 + m) * 512 + n0 + nf * 16 + fr] =
            iv * acc[mf][nf][rr] + NEG_BIG_F * mvv[nf];
    }
}

// ---------------------------------------------------------------------------
extern "C" void kernel_launch(void* const* d_in, const int* in_sizes, int n_in,
                              void* d_out, int out_size, void* d_ws, size_t ws_size,
                              hipStream_t stream)
{
  const float* Q  = (const float*)d_in[0];
  const float* Kx = (const float*)d_in[1];
  const float* V  = (const float*)d_in[2];
  const float* WQ = (const float*)d_in[3];
  const float* WK = (const float*)d_in[4];
  const float* WV = (const float*)d_in[5];
  const int* mask = (const int*)d_in[6];

  const int B = 16, S = 1024, D = 512;
  float* out_f  = (float*)d_out;                      // B*S*D fp32 (final out)
  float* attn_f = out_f + (size_t)B * S * D;          // B*S*S fp32 (final attn)
  unsigned short* Pbuf = (unsigned short*)d_out;      // P'' bf16 aliases out
                                                      // region; pv_gemm clobbers
                                                      // only its own rows after
                                                      // reading them.

  // ws: qb | kb | vt (8.39M ushorts each) | wb (0.79M) | partial | mvsum
  unsigned short* qb = (unsigned short*)d_ws;
  unsigned short* kb = qb + (size_t)B * S * D;
  unsigned short* vt = kb + (size_t)B * S * D;
  unsigned short* wb = vt + (size_t)B * S * D;
  float* partial = (float*)(wb + 786432);             // 16 x 16384 f32
  float* mvsum = partial + 262144;                    // 16 x 512 f32

  cvtW<<<dim3(128, 1, 3), 256, 0, stream>>>(WQ, WK, WV, wb);
  proj_all<<<dim3(512), 512, 0, stream>>>(Q, Kx, V, wb, qb, kb, vt);
  score256<<<dim3(4, 4, 16), 512, 0, stream>>>(qb, kb, mask, Pbuf, partial);
  mv_attn<<<dim3(10240), 256, 0, stream>>>(vt, Pbuf, partial, mask, mvsum, attn_f);
  pv_gemm<<<dim3(16, 1, 16), 512, 0, stream>>>(Pbuf, vt, partial, mvsum, out_f);
}

// Round 9
// 146.962 us; speedup vs baseline: 1.1306x; 1.0148x over previous
//
#include <hip/hip_runtime.h>
#include <hip/hip_bf16.h>

typedef float f32x4 __attribute__((ext_vector_type(4)));
typedef __bf16 bf16x8 __attribute__((ext_vector_type(8)));
typedef unsigned short u16x8 __attribute__((ext_vector_type(8)));
typedef int i32x4 __attribute__((ext_vector_type(4)));

#define NEG_BIG_F (-1000000000.0f)
#define SCALE_F 0.044194173824159216f

__device__ __forceinline__ unsigned short f2bf(float f) {
  unsigned int u = __float_as_uint(f);
  u += 0x7FFFu + ((u >> 16) & 1u);   // round-to-nearest-even
  return (unsigned short)(u >> 16);
}

__device__ __forceinline__ float bf2f(unsigned short h) {
  return __uint_as_float((unsigned int)h << 16);
}

__device__ __forceinline__ u16x8 cvt8(f32x4 a, f32x4 b) {
  u16x8 r;
  r[0] = f2bf(a[0]); r[1] = f2bf(a[1]); r[2] = f2bf(a[2]); r[3] = f2bf(a[3]);
  r[4] = f2bf(b[0]); r[5] = f2bf(b[1]); r[6] = f2bf(b[2]); r[7] = f2bf(b[3]);
  return r;
}

__device__ __forceinline__ void gload16(const void* g, char* l) {
  __builtin_amdgcn_global_load_lds(
      (const __attribute__((address_space(1))) unsigned int*)g,
      (__attribute__((address_space(3))) unsigned int*)l, 16, 0, 0);
}

// ---------------------------------------------------------------------------
// cvtW: three 512x512 fp32 weight matrices -> bf16
// ---------------------------------------------------------------------------
__global__ __launch_bounds__(256) void cvtW(
    const float* __restrict__ w0, const float* __restrict__ w1,
    const float* __restrict__ w2, unsigned short* __restrict__ out)
{
  const float* src = blockIdx.z == 0 ? w0 : (blockIdx.z == 1 ? w1 : w2);
  unsigned short* dst = out + (size_t)blockIdx.z * 262144;
  const int i = (blockIdx.x * 256 + threadIdx.x) * 8;
  f32x4 a = *(const f32x4*)(src + i);
  f32x4 b = *(const f32x4*)(src + i + 4);
  *(u16x8*)&dst[i] = cvt8(a, b);
}

// ---------------------------------------------------------------------------
// proj_all: blocks 0-255 = projqk (256x256 tile), 256-511 = projv (128x256).
// R9: fp32 reg-staging prefetches 2 tiles ahead (pa/pb[2] slots, full unroll
// for static reg indexing) so the write-late ds_write consumes regs loaded
// ~2 phases earlier (~600+cy cover vs HBM ~900cy). Issue order: gloads
// first, then reg loads; counted vmcnt re-derived per-iter.
// ---------------------------------------------------------------------------
__global__ __launch_bounds__(512, 2) void proj_all(
    const float* __restrict__ Q, const float* __restrict__ Kx,
    const float* __restrict__ V, const unsigned short* __restrict__ wb,
    unsigned short* __restrict__ qb, unsigned short* __restrict__ kb,
    unsigned short* __restrict__ vt)
{
  __shared__ __align__(16) unsigned short lds[32768];   // 64 KB pool

  const int bid = blockIdx.x;
  const int tid = threadIdx.x;
  const int lane = tid & 63, wave = tid >> 6;
  const int fr = lane & 15, fq = lane >> 4;

  if (bid < 256) {
    // ---------------- projqk ----------------
    const int z = bid >> 7, rem = bid & 127;
    const float* X = z ? Kx : Q;
    const unsigned short* W = wb + (size_t)z * 262144;
    unsigned short* Y = z ? kb : qb;
    const int m0 = (rem & 63) * 256, n0 = (rem >> 6) * 256;
    const int wr = (wave >> 2) * 128, wc = (wave & 3) * 64;

    unsigned short (*As)[256][32] = (unsigned short (*)[256][32])lds;
    unsigned short (*Bs)[256][32] = (unsigned short (*)[256][32])(lds + 16384);

    f32x4 acc[8][4] = {};

    int arow_s[2], aswz_s[2];
    const float* gAs[2];
    #pragma unroll
    for (int i = 0; i < 2; i++) {
      const int c = tid + 512 * i;
      arow_s[i] = c >> 2;
      aswz_s[i] = ((c & 3) ^ ((arow_s[i] >> 1) & 3)) * 8;
      gAs[i] = X + (size_t)(m0 + arow_s[i]) * 512 + (c & 3) * 8;
    }
    const unsigned short* gB[2]; char* lB[2];
    #pragma unroll
    for (int i = 0; i < 2; i++) {
      const int c = tid + 512 * i, row = c >> 2, slot = c & 3;
      gB[i] = W + (size_t)(n0 + row) * 512 + (slot ^ ((row >> 1) & 3)) * 8;
      lB[i] = (char*)(lds + 16384) + c * 16;
    }

    // prologue: A-regs for tiles 0 and 1; B gload tile 0; ds_write tile 0
    f32x4 pa[2][2][2];    // [slot][pair][half]; tile t -> slot t&1
    #pragma unroll
    for (int i = 0; i < 2; i++) {
      pa[0][i][0] = *(const f32x4*)(gAs[i]);
      pa[0][i][1] = *(const f32x4*)(gAs[i] + 4);
      pa[1][i][0] = *(const f32x4*)(gAs[i] + 32);
      pa[1][i][1] = *(const f32x4*)(gAs[i] + 36);
    }
    #pragma unroll
    for (int i = 0; i < 2; i++) gload16(gB[i], lB[i]);
    #pragma unroll
    for (int i = 0; i < 2; i++)
      *(u16x8*)&As[0][arow_s[i]][aswz_s[i]] = cvt8(pa[0][i][0], pa[0][i][1]);

    #pragma unroll
    for (int t = 0; t < 16; t++) {
      const int cur = t & 1, nxt = cur ^ 1;
      const int kt = t * 32;
      if (t < 15) {          // B gload tile t+1 -> Bs[nxt]
        #pragma unroll
        for (int i = 0; i < 2; i++) gload16(gB[i] + kt + 32, lB[i] + nxt * 16384);
      }
      if (t < 14) {          // A regs tile t+2 -> slot cur (tile t consumed)
        #pragma unroll
        for (int i = 0; i < 2; i++) {
          pa[cur][i][0] = *(const f32x4*)(gAs[i] + kt + 64);
          pa[cur][i][1] = *(const f32x4*)(gAs[i] + kt + 68);
        }
      }
      // drain exactly B(t): oldest 2 of {B(t)2,A(t+1)4,B(t+1)2,A(t+2)4}
      if (t == 0 || t == 14)
        asm volatile("s_waitcnt vmcnt(6) lgkmcnt(0)" ::: "memory");
      else if (t == 15)
        asm volatile("s_waitcnt vmcnt(0) lgkmcnt(0)" ::: "memory");
      else
        asm volatile("s_waitcnt vmcnt(10) lgkmcnt(0)" ::: "memory");
      __builtin_amdgcn_sched_barrier(0);
      __builtin_amdgcn_s_barrier();

      bf16x8 bv[4];
      #pragma unroll
      for (int nf = 0; nf < 4; nf++) {
        const int br = wc + nf * 16 + fr;
        bv[nf] = *(const bf16x8*)&Bs[cur][br][(fq ^ ((br >> 1) & 3)) * 8];
      }
      #pragma unroll
      for (int mf = 0; mf < 8; mf++) {
        const int ar = wr + mf * 16 + fr;
        bf16x8 av = *(const bf16x8*)&As[cur][ar][(fq ^ ((ar >> 1) & 3)) * 8];
        #pragma unroll
        for (int nf = 0; nf < 4; nf++)
          acc[mf][nf] = __builtin_amdgcn_mfma_f32_16x16x32_bf16(av, bv[nf], acc[mf][nf], 0, 0, 0);
      }

      if (t < 15) {          // write-late: tile t+1 regs (loaded at iter t-1)
        #pragma unroll
        for (int i = 0; i < 2; i++)
          *(u16x8*)&As[nxt][arow_s[i]][aswz_s[i]] = cvt8(pa[nxt][i][0], pa[nxt][i][1]);
      }
      __builtin_amdgcn_s_barrier();
    }

    #pragma unroll
    for (int mf = 0; mf < 8; mf++)
      #pragma unroll
      for (int nf = 0; nf < 4; nf++)
        #pragma unroll
        for (int rr = 0; rr < 4; rr++) {
          const int m = m0 + wr + mf * 16 + fq * 4 + rr;
          const int n = n0 + wc + nf * 16 + fr;
          Y[(size_t)m * 512 + n] = f2bf(acc[mf][nf][rr]);
        }
  } else {
    // ---------------- projv ----------------
    const int c0 = bid - 256;
    const int m0 = (c0 & 3) * 128, n0 = ((c0 >> 2) & 3) * 256, b = c0 >> 4;
    const int wr = (wave >> 2) * 64, wc = (wave & 3) * 64;
    const unsigned short* wv = wb + 524288;

    unsigned short (*As)[128][32] = (unsigned short (*)[128][32])lds;
    unsigned short (*Bs)[256][32] = (unsigned short (*)[256][32])(lds + 8192);

    f32x4 acc[4][4] = {};

    const int ar_s = tid >> 2, aslot = tid & 3;
    const unsigned short* gA = wv + (size_t)(m0 + ar_s) * 512 + (aslot ^ ((ar_s >> 1) & 3)) * 8;
    char* lA = (char*)lds + tid * 16;

    int brow_s[2], bswz_s[2];
    const float* gBs[2];
    #pragma unroll
    for (int i = 0; i < 2; i++) {
      const int c = tid + 512 * i;
      brow_s[i] = c >> 2;
      bswz_s[i] = ((c & 3) ^ ((brow_s[i] >> 1) & 3)) * 8;
      gBs[i] = V + ((size_t)b * 1024 + n0 + brow_s[i]) * 512 + (c & 3) * 8;
    }

    // prologue: B-regs tiles 0,1; A gload tile 0; ds_write B tile 0
    f32x4 pb[2][2][2];
    #pragma unroll
    for (int i = 0; i < 2; i++) {
      pb[0][i][0] = *(const f32x4*)(gBs[i]);
      pb[0][i][1] = *(const f32x4*)(gBs[i] + 4);
      pb[1][i][0] = *(const f32x4*)(gBs[i] + 32);
      pb[1][i][1] = *(const f32x4*)(gBs[i] + 36);
    }
    gload16(gA, lA);
    #pragma unroll
    for (int i = 0; i < 2; i++)
      *(u16x8*)&Bs[0][brow_s[i]][bswz_s[i]] = cvt8(pb[0][i][0], pb[0][i][1]);

    #pragma unroll
    for (int t = 0; t < 16; t++) {
      const int cur = t & 1, nxt = cur ^ 1;
      const int kt = t * 32;
      if (t < 15) gload16(gA + kt + 32, lA + nxt * 8192);   // A tile t+1
      if (t < 14) {                                          // B regs tile t+2
        #pragma unroll
        for (int i = 0; i < 2; i++) {
          pb[cur][i][0] = *(const f32x4*)(gBs[i] + kt + 64);
          pb[cur][i][1] = *(const f32x4*)(gBs[i] + kt + 68);
        }
      }
      // drain exactly A(t): oldest 1 of {A(t)1,B(t+1)4,A(t+1)1,B(t+2)4}
      if (t == 0 || t == 14)
        asm volatile("s_waitcnt vmcnt(5) lgkmcnt(0)" ::: "memory");
      else if (t == 15)
        asm volatile("s_waitcnt vmcnt(0) lgkmcnt(0)" ::: "memory");
      else
        asm volatile("s_waitcnt vmcnt(9) lgkmcnt(0)" ::: "memory");
      __builtin_amdgcn_sched_barrier(0);
      __builtin_amdgcn_s_barrier();

      bf16x8 av[4], bv[4];
      #pragma unroll
      for (int mf = 0; mf < 4; mf++) {
        const int ar = wr + mf * 16 + fr;
        av[mf] = *(const bf16x8*)&As[cur][ar][(fq ^ ((ar >> 1) & 3)) * 8];
      }
      #pragma unroll
      for (int nf = 0; nf < 4; nf++) {
        const int br = wc + nf * 16 + fr;
        bv[nf] = *(const bf16x8*)&Bs[cur][br][(fq ^ ((br >> 1) & 3)) * 8];
      }
      #pragma unroll
      for (int mf = 0; mf < 4; mf++)
        #pragma unroll
        for (int nf = 0; nf < 4; nf++)
          acc[mf][nf] = __builtin_amdgcn_mfma_f32_16x16x32_bf16(av[mf], bv[nf], acc[mf][nf], 0, 0, 0);

      if (t < 15) {
        #pragma unroll
        for (int i = 0; i < 2; i++)
          *(u16x8*)&Bs[nxt][brow_s[i]][bswz_s[i]] = cvt8(pb[nxt][i][0], pb[nxt][i][1]);
      }
      __builtin_amdgcn_s_barrier();
    }

    #pragma unroll
    for (int mf = 0; mf < 4; mf++)
      #pragma unroll
      for (int nf = 0; nf < 4; nf++)
        #pragma unroll
        for (int rr = 0; rr < 4; rr++) {
          const int e = m0 + wr + mf * 16 + fq * 4 + rr;
          const int s = n0 + wc + nf * 16 + fr;
          vt[((size_t)b * 512 + e) * 1024 + s] = f2bf(acc[mf][nf][rr]);
        }
  }
}

// ---------------------------------------------------------------------------
// score256: s = (q k^T)/sqrt(512). Writes P''[b][m][k] = mask ? bf16(exp(s))
// : 0 + per-row partial exp-sums. (unchanged from R8 — proven)
// ---------------------------------------------------------------------------
__global__ __launch_bounds__(512, 2) void score256(
    const unsigned short* __restrict__ qb, const unsigned short* __restrict__ kb,
    const int* __restrict__ mask,
    unsigned short* __restrict__ P, float* __restrict__ partial)
{
  __shared__ __align__(16) unsigned short As[2][256][32];
  __shared__ __align__(16) unsigned short Bs[2][256][32];

  const int tid = threadIdx.x, bz = blockIdx.z;
  const int m0 = blockIdx.x * 256, n0 = blockIdx.y * 256;
  const int lane = tid & 63, wave = tid >> 6;
  const int wr = (wave >> 2) * 128, wc = (wave & 3) * 64;
  const int fr = lane & 15, fq = lane >> 4;

  f32x4 acc[8][4] = {};

  const unsigned short* gA[2]; char* lA[2];
  const unsigned short* gB[2]; char* lB[2];
  #pragma unroll
  for (int i = 0; i < 2; i++) {
    const int c = tid + 512 * i, row = c >> 2, slot = c & 3;
    const int sw = (slot ^ ((row >> 1) & 3)) * 8;
    gA[i] = qb + ((size_t)bz * 1024 + m0 + row) * 512 + sw;
    gB[i] = kb + ((size_t)bz * 1024 + n0 + row) * 512 + sw;
    lA[i] = (char*)&As[0][0][0] + c * 16;
    lB[i] = (char*)&Bs[0][0][0] + c * 16;
  }

  #pragma unroll
  for (int i = 0; i < 2; i++) { gload16(gA[i], lA[i]); gload16(gB[i], lB[i]); }

  int cur = 0;
  for (int kt = 0; kt < 512; kt += 32) {
    const int nb = cur ^ 1;
    if (kt < 480) {
      #pragma unroll
      for (int i = 0; i < 2; i++) {
        gload16(gA[i] + kt + 32, lA[i] + nb * 16384);
        gload16(gB[i] + kt + 32, lB[i] + nb * 16384);
      }
      asm volatile("s_waitcnt vmcnt(4) lgkmcnt(0)" ::: "memory");
    } else {
      asm volatile("s_waitcnt vmcnt(0) lgkmcnt(0)" ::: "memory");
    }
    __builtin_amdgcn_sched_barrier(0);
    __builtin_amdgcn_s_barrier();

    bf16x8 bv[4];
    #pragma unroll
    for (int nf = 0; nf < 4; nf++) {
      const int br = wc + nf * 16 + fr;
      bv[nf] = *(const bf16x8*)&Bs[cur][br][(fq ^ ((br >> 1) & 3)) * 8];
    }
    #pragma unroll
    for (int mf = 0; mf < 8; mf++) {
      const int ar = wr + mf * 16 + fr;
      bf16x8 av = *(const bf16x8*)&As[cur][ar][(fq ^ ((ar >> 1) & 3)) * 8];
      #pragma unroll
      for (int nf = 0; nf < 4; nf++)
        acc[mf][nf] = __builtin_amdgcn_mfma_f32_16x16x32_bf16(av, bv[nf], acc[mf][nf], 0, 0, 0);
    }
    __builtin_amdgcn_s_barrier();
    cur = nb;
  }

  int mcol[4];
  #pragma unroll
  for (int nf = 0; nf < 4; nf++)
    mcol[nf] = mask[bz * 1024 + n0 + wc + nf * 16 + fr];

  unsigned short* Pb = P + ((size_t)bz << 20);
  const int slot = blockIdx.y * 4 + (wave & 3);
  #pragma unroll
  for (int mf = 0; mf < 8; mf++) {
    #pragma unroll
    for (int rr = 0; rr < 4; rr++) {
      const int m = m0 + wr + mf * 16 + fq * 4 + rr;
      float e = 0.f;
      #pragma unroll
      for (int nf = 0; nf < 4; nf++) {
        const float ev = __expf(acc[mf][nf][rr] * SCALE_F);
        e += ev;
        Pb[(size_t)m * 1024 + n0 + wc + nf * 16 + fr] =
            mcol[nf] ? f2bf(ev) : (unsigned short)0;
      }
      e += __shfl_xor(e, 1); e += __shfl_xor(e, 2);
      e += __shfl_xor(e, 4); e += __shfl_xor(e, 8);
      if (fr == 0)
        partial[(size_t)slot * 16384 + bz * 1024 + m] = e;
    }
  }
}

// ---------------------------------------------------------------------------
// mv_attn: blocks 0-2047 = mvsum; 2048-10239 = attn_write (inv from partial).
// (unchanged from R8)
// ---------------------------------------------------------------------------
__global__ __launch_bounds__(256) void mv_attn(
    const unsigned short* __restrict__ vt, const unsigned short* __restrict__ P,
    const float* __restrict__ partial, const int* __restrict__ mask,
    float* __restrict__ mvsum, float* __restrict__ attn)
{
  const int bid = blockIdx.x;
  const int tid = threadIdx.x;
  if (bid < 2048) {
    const int row = bid * 4 + (tid >> 6);   // 0..8191 = b*512+e
    const int b = row >> 9;
    const int lane = tid & 63;
    const unsigned short* vr = vt + (size_t)row * 1024 + lane * 16;
    const int* mr = mask + b * 1024 + lane * 16;
    u16x8 v0 = *(const u16x8*)(vr);
    u16x8 v1 = *(const u16x8*)(vr + 8);
    float s = 0.f;
    #pragma unroll
    for (int j = 0; j < 8; j++) {
      if (!mr[j])     s += bf2f(v0[j]);
      if (!mr[8 + j]) s += bf2f(v1[j]);
    }
    #pragma unroll
    for (int o = 32; o > 0; o >>= 1) s += __shfl_xor(s, o);
    if (lane == 0) mvsum[row] = s;
  } else {
    const int ab = bid - 2048;              // 0..8191, covers 2 q-rows each
    __shared__ float s_inv[2];
    const int row0 = ab * 2;
    if (tid < 2) {
      float s = 0.f;
      #pragma unroll
      for (int p = 0; p < 16; p++) s += partial[(size_t)p * 16384 + row0 + tid];
      s_inv[tid] = 1.0f / s;
    }
    __syncthreads();
    const size_t base = (size_t)ab * 2048 + tid * 8;
    const int b = (int)(base >> 20);
    const int k0 = (int)(base & 1023);
    const u16x8 p8 = *(const u16x8*)(P + base);
    const float iv = s_inv[tid >> 7];
    const int* mr = mask + b * 1024 + k0;
    const i32x4 ma = *(const i32x4*)(mr);
    const i32x4 mb = *(const i32x4*)(mr + 4);
    f32x4 o0, o1;
    o0[0] = ma[0] ? bf2f(p8[0]) * iv : NEG_BIG_F;
    o0[1] = ma[1] ? bf2f(p8[1]) * iv : NEG_BIG_F;
    o0[2] = ma[2] ? bf2f(p8[2]) * iv : NEG_BIG_F;
    o0[3] = ma[3] ? bf2f(p8[3]) * iv : NEG_BIG_F;
    o1[0] = mb[0] ? bf2f(p8[4]) * iv : NEG_BIG_F;
    o1[1] = mb[1] ? bf2f(p8[5]) * iv : NEG_BIG_F;
    o1[2] = mb[2] ? bf2f(p8[6]) * iv : NEG_BIG_F;
    o1[3] = mb[3] ? bf2f(p8[7]) * iv : NEG_BIG_F;
    *(f32x4*)(attn + base) = o0;
    *(f32x4*)(attn + base + 4) = o1;
  }
}

// ---------------------------------------------------------------------------
// pv_gemm: out[b][m][e] = inv[m]*(P''·vt^T) - 1e9*mvsum[b][e].
// (unchanged from R8)
// ---------------------------------------------------------------------------
__global__ __launch_bounds__(512) void pv_gemm(
    const unsigned short* __restrict__ P, const unsigned short* __restrict__ vt,
    const float* __restrict__ partial, const float* __restrict__ mvsum,
    float* __restrict__ out)
{
  __shared__ __align__(16) unsigned short As[2][64][32];   // 8 KB
  __shared__ __align__(16) unsigned short Bs[2][512][32];  // 64 KB
  __shared__ float inv_l[64];

  const int tid = threadIdx.x;
  const int bz = blockIdx.z, m0 = blockIdx.x * 64;
  const int lane = tid & 63, wave = tid >> 6;
  const int n0 = wave * 64;
  const int fr = lane & 15, fq = lane >> 4;

  f32x4 acc[4][4] = {};

  if (tid < 64) {
    float s = 0.f;
    #pragma unroll
    for (int p = 0; p < 16; p++) s += partial[(size_t)p * 16384 + bz * 1024 + m0 + tid];
    inv_l[tid] = 1.0f / s;
  }

  const unsigned short* gA = nullptr; char* lA = nullptr;
  if (tid < 256) {
    const int row = tid >> 2, slot = tid & 3;
    gA = P + ((size_t)bz << 20) + (size_t)(m0 + row) * 1024 + (slot ^ ((row >> 1) & 3)) * 8;
    lA = (char*)&As[0][0][0] + tid * 16;
  }
  const unsigned short* gB[4]; char* lB[4];
  #pragma unroll
  for (int i = 0; i < 4; i++) {
    const int c = tid + 512 * i, row = c >> 2, slot = c & 3;
    gB[i] = vt + ((size_t)bz * 512 + row) * 1024 + (slot ^ ((row >> 1) & 3)) * 8;
    lB[i] = (char*)&Bs[0][0][0] + c * 16;
  }

  if (tid < 256) gload16(gA, lA);
  #pragma unroll
  for (int i = 0; i < 4; i++) gload16(gB[i], lB[i]);

  int cur = 0;
  for (int t = 0; t < 32; t++) {
    const int nb = cur ^ 1;
    const int kt = t * 32;
    if (t < 31) {
      if (tid < 256) gload16(gA + kt + 32, lA + nb * 4096);
      #pragma unroll
      for (int i = 0; i < 4; i++) gload16(gB[i] + kt + 32, lB[i] + nb * 32768);
      if (wave < 4) asm volatile("s_waitcnt vmcnt(5) lgkmcnt(0)" ::: "memory");
      else          asm volatile("s_waitcnt vmcnt(4) lgkmcnt(0)" ::: "memory");
    } else {
      asm volatile("s_waitcnt vmcnt(0) lgkmcnt(0)" ::: "memory");
    }
    __builtin_amdgcn_sched_barrier(0);
    __builtin_amdgcn_s_barrier();

    bf16x8 af[4], bv[4];
    #pragma unroll
    for (int mf = 0; mf < 4; mf++) {
      const int ar = mf * 16 + fr;
      af[mf] = *(const bf16x8*)&As[cur][ar][(fq ^ ((ar >> 1) & 3)) * 8];
    }
    #pragma unroll
    for (int nf = 0; nf < 4; nf++) {
      const int br = n0 + nf * 16 + fr;
      bv[nf] = *(const bf16x8*)&Bs[cur][br][(fq ^ ((br >> 1) & 3)) * 8];
    }
    #pragma unroll
    for (int mf = 0; mf < 4; mf++)
      #pragma unroll
      for (int nf = 0; nf < 4; nf++)
        acc[mf][nf] = __builtin_amdgcn_mfma_f32_16x16x32_bf16(af[mf], bv[nf], acc[mf][nf], 0, 0, 0);
    __builtin_amdgcn_s_barrier();
    cur = nb;
  }

  float mvv[4];
  #pragma unroll
  for (int nf = 0; nf < 4; nf++)
    mvv[nf] = mvsum[bz * 512 + n0 + nf * 16 + fr];
  #pragma unroll
  for (int mf = 0; mf < 4; mf++)
    #pragma unroll
    for (int rr = 0; rr < 4; rr++) {
      const int m = m0 + mf * 16 + fq * 4 + rr;
      const float iv = inv_l[mf * 16 + fq * 4 + rr];
      #pragma unroll
      for (int nf = 0; nf < 4; nf++)
        out[((size_t)bz * 1024 + m) * 512 + n0 + nf * 16 + fr] =
            iv * acc[mf][nf][rr] + NEG_BIG_F * mvv[nf];
    }
}

// ---------------------------------------------------------------------------
extern "C" void kernel_launch(void* const* d_in, const int* in_sizes, int n_in,
                              void* d_out, int out_size, void* d_ws, size_t ws_size,
                              hipStream_t stream)
{
  const float* Q  = (const float*)d_in[0];
  const float* Kx = (const float*)d_in[1];
  const float* V  = (const float*)d_in[2];
  const float* WQ = (const float*)d_in[3];
  const float* WK = (const float*)d_in[4];
  const float* WV = (const float*)d_in[5];
  const int* mask = (const int*)d_in[6];

  const int B = 16, S = 1024, D = 512;
  float* out_f  = (float*)d_out;                      // B*S*D fp32 (final out)
  float* attn_f = out_f + (size_t)B * S * D;          // B*S*S fp32 (final attn)
  unsigned short* Pbuf = (unsigned short*)d_out;      // P'' bf16 aliases out region

  // ws: qb | kb | vt (8.39M ushorts each) | wb (0.79M) | partial | mvsum
  unsigned short* qb = (unsigned short*)d_ws;
  unsigned short* kb = qb + (size_t)B * S * D;
  unsigned short* vt = kb + (size_t)B * S * D;
  unsigned short* wb = vt + (size_t)B * S * D;
  float* partial = (float*)(wb + 786432);             // 16 x 16384 f32
  float* mvsum = partial + 262144;                    // 16 x 512 f32

  cvtW<<<dim3(128, 1, 3), 256, 0, stream>>>(WQ, WK, WV, wb);
  proj_all<<<dim3(512), 512, 0, stream>>>(Q, Kx, V, wb, qb, kb, vt);
  score256<<<dim3(4, 4, 16), 512, 0, stream>>>(qb, kb, mask, Pbuf, partial);
  mv_attn<<<dim3(10240), 256, 0, stream>>>(vt, Pbuf, partial, mask, mvsum, attn_f);
  pv_gemm<<<dim3(16, 1, 16), 512, 0, stream>>>(Pbuf, vt, partial, mvsum, out_f);
}